// Round 11
// baseline (107.213 us; speedup 1.0000x reference)
//
#include <hip/hip_runtime.h>
#include <hip/hip_bf16.h>
#include <math.h>

// Problem constants
#define B2      128
#define NSEQ    256
#define DMODEL  256
#define NHEAD   8
#define CDIM    32
#define HC      256
#define NROWS   (B2*NSEQ)    // 32768
#define SCALING 0.17677669529663687f  // 1/sqrt(32)

typedef __attribute__((ext_vector_type(8))) short bf16x8;
typedef __attribute__((ext_vector_type(4))) float f32x4;

static __device__ __forceinline__ ushort f2bf(float f) {       // RNE (weights)
    __hip_bfloat16 b = __float2bfloat16(f);
    ushort r; __builtin_memcpy(&r, &b, 2); return r;
}
static __device__ __forceinline__ ushort f2bf_fast(float f) {  // round-half-up
    uint u = __builtin_bit_cast(uint, f);
    return (ushort)((u + 0x8000u) >> 16);
}
static __device__ __forceinline__ uint fpack2(float a, float b) {
    const uint ua = __builtin_bit_cast(uint, a) + 0x8000u;
    const uint ub = __builtin_bit_cast(uint, b) + 0x8000u;
    return (ua >> 16) | (ub & 0xFFFF0000u);
}
static __device__ __forceinline__ float bf2f(ushort u) {
    __hip_bfloat16 b; __builtin_memcpy(&b, &u, 2); return __bfloat162float(b);
}
static __device__ __forceinline__ void gload_lds16(const void* g, void* l) {
    __builtin_amdgcn_global_load_lds((const __attribute__((address_space(1))) void*)g,
                                     (__attribute__((address_space(3))) void*)l, 16, 0, 0);
}

// ---------------- Kernel 0: weight fp32 -> bf16 conversion (tiny) ----------------
__global__ __launch_bounds__(256) void convertW_kernel(
    const float* __restrict__ Wqkv, const float* __restrict__ Wg,
    const float* __restrict__ Wo,
    ushort* __restrict__ wqkvgb, ushort* __restrict__ wob)
{
    const int NQ = 196608 / 4, NG = 65536 / 4, NO = 65536 / 4;  // quads
    const int idx = blockIdx.x * 256 + threadIdx.x;             // grid 320 = exact
    const float* src; ushort* dst; int off; float scale = 1.0f;
    if (idx < NQ)           { src = Wqkv; dst = wqkvgb;          off = idx;
                              if (off < 16384) scale = SCALING; }   // q rows pre-scaled
    else if (idx < NQ + NG) { src = Wg;   dst = wqkvgb + 196608; off = idx - NQ; }
    else                    { src = Wo;   dst = wob;             off = idx - NQ - NG; }
    float4 v = ((const float4*)src)[off];
    union { ushort u[4]; uint2 q; } p;
    p.u[0] = f2bf(v.x * scale); p.u[1] = f2bf(v.y * scale);
    p.u[2] = f2bf(v.z * scale); p.u[3] = f2bf(v.w * scale);
    *(uint2*)(dst + (size_t)off * 4) = p.q;
}

// ---------------- Kernel 1: QKV+gate projection, barrier-free W-in-VGPR ----------
// One block owns 64 m-rows, loops segs {q,k,v,gate}. X staged to LDS once
// (32KB swizzled, ONE barrier). W A-fragments loaded straight into registers
// (4-deep rotating buffer, compiler-counted waits, no LDS, no barriers).
// Epilogue transpose tile T (32KB) is wave-local in cols -> barrier-free.
__global__ __launch_bounds__(256) void qkvg_mfma_kernel(
    const float* __restrict__ X,       // fp32 [32768][256]
    const ushort* __restrict__ Wb,     // bf16 [1024][256] (q rows pre-scaled)
    const float* __restrict__ gbias,   // [256]
    ushort* __restrict__ q_ws,         // bf16 [128*8][256][32]
    ushort* __restrict__ k_ws,
    ushort* __restrict__ v_ws,
    ushort* __restrict__ g_ws)         // bf16 [32768][256]
{
    __shared__ ushort S[32768];        // 64KB: T overlay (32KB) | X (32KB)
    ushort* const Xls = S + 16384;

    const int tid  = threadIdx.x;
    const int w    = tid >> 6;
    const int lane = tid & 63;
    const int lj   = lane & 15;
    const int lg   = lane >> 4;
    const int m0   = blockIdx.x * 64;

    const int xsl  = ((lg ^ ((lj >> 1) & 3)) << 3);

    // ---- W fragment pipeline: 4-deep rotating register buffer ----
    bf16x8 wf[4][4];
    const ushort* const wbase = Wb + (size_t)(w * 64 + lj) * 256 + lg * 8;
    #define WLOAD(s, b) do {                                                     \
        if ((s) < 32) {                                                          \
            const ushort* wp = wbase + (size_t)((s) >> 3) * 65536 + ((s) & 7) * 32; \
            _Pragma("unroll")                                                    \
            for (int i = 0; i < 4; ++i)                                          \
                wf[b][i] = *(const bf16x8*)(wp + i * 16 * 256);                  \
        } } while (0)

    WLOAD(0, 0); WLOAD(1, 1); WLOAD(2, 2);

    // ---- stage X once: fp32 global -> fast cvt -> LDS, swizzled content ----
    {
        const int row  = tid >> 2;                      // 0..63
        const int slot = tid & 3;                       // 16B slot
        const int g8   = (slot ^ ((row >> 1) & 3)) * 8; // k-subgroup content
        const float* xsrc = X + (size_t)(m0 + row) * 256 + g8;
        ushort* xdst = Xls + row * 32 + slot * 8;
        #pragma unroll
        for (int t = 0; t < 8; ++t) {
            const float4 a = *(const float4*)(xsrc + t * 32);
            const float4 b = *(const float4*)(xsrc + t * 32 + 4);
            uint4 pk;
            pk.x = fpack2(a.x, a.y); pk.y = fpack2(a.z, a.w);
            pk.z = fpack2(b.x, b.y); pk.w = fpack2(b.z, b.w);
            *(uint4*)(xdst + t * 2048) = pk;
        }
    }
    __syncthreads();   // the ONLY block-wide barrier: X ready for all waves

    const int b2 = m0 >> 8;
    const int n0 = m0 & 255;
    uint* T = (uint*)S;

    for (int seg = 0; seg < 4; ++seg) {
        f32x4 acc[4][4];
        #pragma unroll
        for (int i = 0; i < 4; ++i)
            #pragma unroll
            for (int j = 0; j < 4; ++j) acc[i][j] = (f32x4){0.f, 0.f, 0.f, 0.f};

        #pragma unroll
        for (int tt = 0; tt < 8; ++tt) {
            const int s = seg * 8 + tt;
            WLOAD(s + 3, (tt + 3) & 3);
            bf16x8 bfr[4];
            #pragma unroll
            for (int j = 0; j < 4; ++j)
                bfr[j] = *(const bf16x8*)(Xls + tt * 2048 + (j * 16 + lj) * 32 + xsl);
            #pragma unroll
            for (int i = 0; i < 4; ++i)
                #pragma unroll
                for (int j = 0; j < 4; ++j)
                    acc[i][j] = __builtin_amdgcn_mfma_f32_16x16x32_bf16(wf[tt & 3][i], bfr[j], acc[i][j], 0, 0, 0);
        }

        // ---- epilogue stage 1: acc -> T[ml][el] (wave-local cols w*64..+63) ----
        #pragma unroll
        for (int i = 0; i < 4; ++i) {
            const int el0 = w * 64 + i * 16 + lg * 4;
            #pragma unroll
            for (int j = 0; j < 4; ++j) {
                const int ml = j * 16 + lj;
                uint2 pk;
                if (seg == 3) {
                    float z0 = acc[i][j][0] + gbias[el0 + 0];
                    float z1 = acc[i][j][1] + gbias[el0 + 1];
                    float z2 = acc[i][j][2] + gbias[el0 + 2];
                    float z3 = acc[i][j][3] + gbias[el0 + 3];
                    pk.x = fpack2(1.f / (1.f + __expf(-z0)), 1.f / (1.f + __expf(-z1)));
                    pk.y = fpack2(1.f / (1.f + __expf(-z2)), 1.f / (1.f + __expf(-z3)));
                } else {
                    pk.x = fpack2(acc[i][j][0], acc[i][j][1]);
                    pk.y = fpack2(acc[i][j][2], acc[i][j][3]);
                }
                const int wd = (ml * 128 + (el0 >> 1)) ^ ((ml & 7) << 2);
                *(uint2*)(T + wd) = pk;
            }
        }
        // no barrier: each wave reads back only the cols it wrote (lgkmcnt by compiler)

        // ---- epilogue stage 2: LDS -> global, coalesced, wave-local ----
        if (seg < 3) {
            ushort* base = (seg == 0) ? q_ws : (seg == 1) ? k_ws : v_ws;
            #pragma unroll
            for (int hh = 0; hh < 2; ++hh) {
                const int h = w * 2 + hh;   // heads in this wave's col slice
                ushort* gdst = base + ((size_t)(b2 * 8 + h) * 256 + n0) * 32;
                #pragma unroll
                for (int it = 0; it < 4; ++it) {
                    const int ml = it * 16 + (lane >> 2);
                    const int cq = lane & 3;
                    const int wd = (ml * 128 + h * 16 + cq * 4) ^ ((ml & 7) << 2);
                    const uint4 d = *(const uint4*)(T + wd);
                    *(uint4*)(gdst + (size_t)ml * 32 + cq * 8) = d;
                }
            }
        } else {
            // gate: wave w covers e-cols w*64..w*64+63 of every row
            #pragma unroll
            for (int it = 0; it < 8; ++it) {
                const int ml  = it * 8 + (lane >> 3);
                const int sub = lane & 7;
                const int wd  = (ml * 128 + w * 32 + sub * 4) ^ ((ml & 7) << 2);
                const uint4 d = *(const uint4*)(T + wd);
                *(uint4*)(g_ws + (size_t)(m0 + ml) * 256 + w * 64 + sub * 8) = d;
            }
        }
        // no barrier: T reuse next seg is wave-serial
    }
    #undef WLOAD
}

// ---------------- Kernel 2: MFMA attention (r10, unchanged) ----------
#define SWZ(c) ((((c) >> 2) & 3) << 5)

__global__ __launch_bounds__(512) void attn_mfma_kernel(
    const ushort* __restrict__ q_ws,
    const ushort* __restrict__ k_ws,
    const ushort* __restrict__ v_ws,
    const ushort* __restrict__ g_ws,
    const float* __restrict__ bias,   // [8][256][256]
    const float* __restrict__ mask,   // [128][256]
    ushort* __restrict__ wa_ws)       // bf16 [32768][256]
{
    __shared__ ushort Ks[256 * 32];
    __shared__ ushort Vt[32 * 256];
    __shared__ ushort Pl[8 * 1024];

    const int tid  = threadIdx.x;
    const int bh   = blockIdx.x >> 1;
    const int half = blockIdx.x & 1;
    const int b2   = bh >> 3;
    const int h    = bh & 7;
    const int w    = tid >> 6;
    const int lane = tid & 63;
    const int lj   = lane & 15;
    const int lg   = lane >> 4;

    // stage K via direct global->LDS (linear)
    {
        const char* gk = (const char*)(k_ws + (size_t)bh * 8192);
        gload_lds16(gk + tid * 16,        (char*)Ks + w * 1024);
        gload_lds16(gk + 8192 + tid * 16, (char*)Ks + 8192 + w * 1024);
    }
    // stage V transposed (register path, swizzled scatter)
    {
        const int cq = tid & 3;
        #pragma unroll
        for (int it = 0; it < 2; ++it) {
            const int n = it * 128 + (tid >> 2);
            uint4 v = *(const uint4*)(v_ws + (size_t)bh * 8192 + n * 32 + cq * 8);
            const ushort* pv = (const ushort*)&v;
            #pragma unroll
            for (int e = 0; e < 8; ++e) {
                const int c = cq * 8 + e;
                const int byte = c * 512 + ((2 * n) ^ SWZ(c));
                Vt[byte >> 1] = pv[e];
            }
        }
    }

    const int q0 = half * 128 + w * 16;
    const bf16x8 qf = *(const bf16x8*)(q_ws + (size_t)bh * 8192 + (size_t)(q0 + lj) * 32 + lg * 8);

    // accumulator init: bias + mask (coalesced), before the barrier
    f32x4 acc[16];
    const float* bbase = bias + (size_t)h * 65536;
    const float* mrow  = mask + (size_t)b2 * 256;
    #pragma unroll
    for (int t = 0; t < 16; ++t) {
        const int col = t * 16 + lj;
        const float mterm = (mrow[col] - 1.0f) * 1e9f;
        #pragma unroll
        for (int r = 0; r < 4; ++r) {
            const int qrow = q0 + lg * 4 + r;
            acc[t][r] = bbase[(size_t)qrow * 256 + col] + mterm;
        }
    }

    __syncthreads();

    #pragma unroll
    for (int t = 0; t < 16; ++t) {
        const bf16x8 kf = *(const bf16x8*)(Ks + (t * 16 + lj) * 32 + lg * 8);
        acc[t] = __builtin_amdgcn_mfma_f32_16x16x32_bf16(qf, kf, acc[t], 0, 0, 0);
    }

    // no-max softmax: exp + per-row sum (rows r; 16 lanes share a row)
    float s[4] = {0.f, 0.f, 0.f, 0.f};
    #pragma unroll
    for (int t = 0; t < 16; ++t)
        #pragma unroll
        for (int r = 0; r < 4; ++r) {
            const float e = __expf(acc[t][r]);
            acc[t][r] = e;
            s[r] += e;
        }
    float inv[4];
    #pragma unroll
    for (int r = 0; r < 4; ++r) {
        float sr = s[r];
        sr += __shfl_xor(sr, 1);
        sr += __shfl_xor(sr, 2);
        sr += __shfl_xor(sr, 4);
        sr += __shfl_xor(sr, 8);
        inv[r] = 1.0f / sr;
    }

    ushort* PlW = Pl + w * 1024;
    f32x4 o0 = {0.f, 0.f, 0.f, 0.f};
    f32x4 o1 = {0.f, 0.f, 0.f, 0.f};
    #pragma unroll
    for (int ch = 0; ch < 4; ++ch) {
        #pragma unroll
        for (int tt = 0; tt < 4; ++tt) {
            const int t = ch * 4 + tt;
            #pragma unroll
            for (int r = 0; r < 4; ++r) {
                const int row  = lg * 4 + r;
                const int byte = row * 128 + ((32 * tt + 2 * lj) ^ (lg << 5));
                PlW[byte >> 1] = f2bf_fast(acc[t][r]);
            }
        }
        #pragma unroll
        for (int kk = 0; kk < 2; ++kk) {
            const int abyte = lj * 128 + ((64 * kk + 16 * lg) ^ SWZ(lj));
            const bf16x8 pa = *(const bf16x8*)(PlW + (abyte >> 1));
            const int ks = ch * 2 + kk;
            {
                const int cr = lj;
                const int vbyte = cr * 512 + ((64 * ks + 16 * lg) ^ SWZ(cr));
                const bf16x8 vb = *(const bf16x8*)(Vt + (vbyte >> 1));
                o0 = __builtin_amdgcn_mfma_f32_16x16x32_bf16(pa, vb, o0, 0, 0, 0);
            }
            {
                const int cr = 16 + lj;
                const int vbyte = cr * 512 + ((64 * ks + 16 * lg) ^ SWZ(cr));
                const bf16x8 vb = *(const bf16x8*)(Vt + (vbyte >> 1));
                o1 = __builtin_amdgcn_mfma_f32_16x16x32_bf16(pa, vb, o1, 0, 0, 0);
            }
        }
    }

    #pragma unroll
    for (int r = 0; r < 4; ++r) {
        const int qrow = q0 + lg * 4 + r;
        const size_t rowbase = ((size_t)(b2 * 256 + qrow)) * 256 + h * 32;
        {
            const float gv = bf2f(g_ws[rowbase + lj]);
            wa_ws[rowbase + lj] = f2bf_fast(o0[r] * inv[r] * gv);
        }
        {
            const float gv = bf2f(g_ws[rowbase + 16 + lj]);
            wa_ws[rowbase + 16 + lj] = f2bf_fast(o1[r] * inv[r] * gv);
        }
    }
}

// ---------------- Kernel 3: MFMA output projection (r10, unchanged) ----------------
__global__ __launch_bounds__(256) void out_mfma_kernel(
    const ushort* __restrict__ WA,   // bf16 [32768][256]
    const ushort* __restrict__ Wob,  // bf16 [256][256]
    const float* __restrict__ bo,    // [256]
    float* __restrict__ out)         // [32768][256]
{
    __shared__ ushort S[20480];
    ushort* const Obuf[2] = { S,        S + 10240 };
    ushort* const Abuf[2] = { S + 8192, S + 18432 };

    const int tid  = threadIdx.x;
    const int w    = tid >> 6;
    const int lane = tid & 63;
    const int lj   = lane & 15;
    const int lg   = lane >> 4;
    const int m0   = blockIdx.x * 64;

    f32x4 acc[4][4];
    #pragma unroll
    for (int i = 0; i < 4; ++i)
        #pragma unroll
        for (int j = 0; j < 4; ++j) acc[i][j] = (f32x4){0.f, 0.f, 0.f, 0.f};

    const int srow = lane >> 2;
    const int scol = (((lane & 3) ^ ((lane >> 3) & 3)) << 3);
    const int xsl  = ((lg ^ ((lj >> 1) & 3)) << 3);

    #define OSTAGE(Odst, Adst, kk) do {                                          \
        _Pragma("unroll")                                                        \
        for (int c = 0; c < 4; ++c) {                                            \
            const int ci = w * 4 + c;                                            \
            gload_lds16(Wob + (size_t)(ci * 16 + srow) * 256 + (kk) + scol,      \
                        (char*)(Odst) + ci * 1024);                              \
        }                                                                        \
        gload_lds16(WA + (size_t)(m0 + w * 16 + srow) * 256 + (kk) + scol,       \
                    (char*)(Adst) + w * 1024);                                   \
    } while (0)

    OSTAGE(Obuf[0], Abuf[0], 0);
    asm volatile("s_waitcnt vmcnt(0)" ::: "memory");
    __builtin_amdgcn_s_barrier();

    #pragma unroll
    for (int t = 0; t < 8; ++t) {
        ushort* Oc = Obuf[t & 1];
        ushort* Ac = Abuf[t & 1];
        if (t < 7) OSTAGE(Obuf[(t + 1) & 1], Abuf[(t + 1) & 1], (t + 1) * 32);
        bf16x8 af[4], bfr[4];
        #pragma unroll
        for (int i = 0; i < 4; ++i)
            af[i] = *(const bf16x8*)(Ac + (i * 16 + lj) * 32 + xsl);
        #pragma unroll
        for (int j = 0; j < 4; ++j)
            bfr[j] = *(const bf16x8*)(Oc + (w * 64 + j * 16 + lj) * 32 + xsl);
        #pragma unroll
        for (int i = 0; i < 4; ++i)
            #pragma unroll
            for (int j = 0; j < 4; ++j)
                acc[i][j] = __builtin_amdgcn_mfma_f32_16x16x32_bf16(af[i], bfr[j], acc[i][j], 0, 0, 0);
        asm volatile("s_waitcnt vmcnt(0)" ::: "memory");
        __builtin_amdgcn_s_barrier();
    }
    #undef OSTAGE

    #pragma unroll
    for (int i = 0; i < 4; ++i) {
        #pragma unroll
        for (int r = 0; r < 4; ++r) {
            const int m = m0 + i * 16 + lg * 4 + r;
            #pragma unroll
            for (int j = 0; j < 4; ++j) {
                const int o = w * 64 + j * 16 + lj;
                out[(size_t)m * 256 + o] = acc[i][j][r] + bo[o];
            }
        }
    }
}

extern "C" void kernel_launch(void* const* d_in, const int* in_sizes, int n_in,
                              void* d_out, int out_size, void* d_ws, size_t ws_size,
                              hipStream_t stream) {
    const float* in_data = (const float*)d_in[0];
    const float* mask    = (const float*)d_in[1];
    const float* nb_bias = (const float*)d_in[2];
    const float* w_qkv   = (const float*)d_in[3];
    const float* w_gate  = (const float*)d_in[4];
    const float* g_bias  = (const float*)d_in[5];
    const float* w_o     = (const float*)d_in[6];
    const float* b_o     = (const float*)d_in[7];
    float* out = (float*)d_out;

    ushort* ws = (ushort*)d_ws;
    const size_t per_head = (size_t)B2 * NHEAD * NSEQ * CDIM;  // 8,388,608
    ushort* q_ws   = ws;
    ushort* k_ws   = q_ws + per_head;
    ushort* v_ws   = k_ws + per_head;
    ushort* g_ws   = v_ws + per_head;                 // [32768][256]
    ushort* wa_ws  = g_ws + (size_t)NROWS * HC;
    ushort* wqkvgb = wa_ws + (size_t)NROWS * HC;      // [1024][256]
    ushort* wob    = wqkvgb + 1024 * 256;             // [256][256]

    convertW_kernel<<<dim3(320), 256, 0, stream>>>(
        w_qkv, w_gate, w_o, wqkvgb, wob);

    qkvg_mfma_kernel<<<dim3(NROWS / 64), 256, 0, stream>>>(
        in_data, wqkvgb, g_bias, q_ws, k_ws, v_ws, g_ws);

    attn_mfma_kernel<<<dim3(B2 * NHEAD * 2), 512, 0, stream>>>(
        q_ws, k_ws, v_ws, g_ws, nb_bias, mask, wa_ws);

    out_mfma_kernel<<<dim3(NROWS / 64), 256, 0, stream>>>(
        wa_ws, wob, b_o, out);
}

// Round 12
// 89.928 us; speedup vs baseline: 1.1922x; 1.1922x over previous
//
#include <hip/hip_runtime.h>
#include <hip/hip_bf16.h>
#include <math.h>

// Problem constants
#define B2      128
#define NSEQ    256
#define DMODEL  256
#define NHEAD   8
#define CDIM    32
#define HC      256
#define NROWS   (B2*NSEQ)    // 32768
#define SCALING 0.17677669529663687f  // 1/sqrt(32)

typedef __attribute__((ext_vector_type(8))) short bf16x8;
typedef __attribute__((ext_vector_type(4))) float f32x4;

static __device__ __forceinline__ ushort f2bf(float f) {       // RNE (weights)
    __hip_bfloat16 b = __float2bfloat16(f);
    ushort r; __builtin_memcpy(&r, &b, 2); return r;
}
static __device__ __forceinline__ ushort f2bf_fast(float f) {  // round-half-up
    uint u = __builtin_bit_cast(uint, f);
    return (ushort)((u + 0x8000u) >> 16);
}
static __device__ __forceinline__ uint fpack2(float a, float b) {
    const uint ua = __builtin_bit_cast(uint, a) + 0x8000u;
    const uint ub = __builtin_bit_cast(uint, b) + 0x8000u;
    return (ua >> 16) | (ub & 0xFFFF0000u);
}
static __device__ __forceinline__ float bf2f(ushort u) {
    __hip_bfloat16 b; __builtin_memcpy(&b, &u, 2); return __bfloat162float(b);
}
static __device__ __forceinline__ void gload_lds16(const void* g, void* l) {
    __builtin_amdgcn_global_load_lds((const __attribute__((address_space(1))) void*)g,
                                     (__attribute__((address_space(3))) void*)l, 16, 0, 0);
}

// ---------------- Kernel 0: weight fp32 -> bf16 conversion (tiny) ----------------
__global__ __launch_bounds__(256) void convertW_kernel(
    const float* __restrict__ Wqkv, const float* __restrict__ Wg,
    const float* __restrict__ Wo,
    ushort* __restrict__ wqkvgb, ushort* __restrict__ wob)
{
    const int NQ = 196608 / 4, NG = 65536 / 4, NO = 65536 / 4;  // quads
    const int idx = blockIdx.x * 256 + threadIdx.x;             // grid 320 = exact
    const float* src; ushort* dst; int off; float scale = 1.0f;
    if (idx < NQ)           { src = Wqkv; dst = wqkvgb;          off = idx;
                              if (off < 16384) scale = SCALING; }   // q rows pre-scaled
    else if (idx < NQ + NG) { src = Wg;   dst = wqkvgb + 196608; off = idx - NQ; }
    else                    { src = Wo;   dst = wob;             off = idx - NQ - NG; }
    float4 v = ((const float4*)src)[off];
    union { ushort u[4]; uint2 q; } p;
    p.u[0] = f2bf(v.x * scale); p.u[1] = f2bf(v.y * scale);
    p.u[2] = f2bf(v.z * scale); p.u[3] = f2bf(v.w * scale);
    *(uint2*)(dst + (size_t)off * 4) = p.q;
}

// ---------------- Kernel 1: QKV+gate projection, 3-ring counted-vmcnt ----------
// One block owns 64 m-rows, loops segs {q,k,v,gate}. X staged to LDS once.
// W pipeline: 3-buffer LDS ring, stage(t+2) issued at step t, in-loop wait
// vmcnt(4) (never 0 except t=7). Next-seg stage0 overlaps the epilogue.
// Epilogue transpose tile T overlays ring bufs 1+2.
__global__ __launch_bounds__(256) void qkvg_mfma_kernel(
    const float* __restrict__ X,       // fp32 [32768][256]
    const ushort* __restrict__ Wb,     // bf16 [1024][256] (q rows pre-scaled)
    const float* __restrict__ gbias,   // [256]
    ushort* __restrict__ q_ws,         // bf16 [128*8][256][32]
    ushort* __restrict__ k_ws,
    ushort* __restrict__ v_ws,
    ushort* __restrict__ g_ws)         // bf16 [32768][256]
{
    __shared__ ushort S[40960];        // 80KB: W ring 3x16KB + X 32KB
    ushort* const Wbuf[3] = { S, S + 8192, S + 16384 };
    ushort* const Xls = S + 24576;

    const int tid  = threadIdx.x;
    const int w    = tid >> 6;
    const int lane = tid & 63;
    const int lj   = lane & 15;
    const int lg   = lane >> 4;
    const int m0   = blockIdx.x * 64;

    const int srow = lane >> 2;
    const int scol = (((lane & 3) ^ ((lane >> 3) & 3)) << 3);
    const int xsl  = ((lg ^ ((lj >> 1) & 3)) << 3);

    #define WSTAGE(dst, seg, t) do {                                             \
        _Pragma("unroll")                                                        \
        for (int c = 0; c < 4; ++c) {                                            \
            const int ci = w * 4 + c;                                            \
            gload_lds16(Wb + (size_t)((seg) * 256 + ci * 16 + srow) * 256 + (t) * 32 + scol, \
                        (char*)(dst) + ci * 1024);                               \
        } } while (0)

    // ---- stage X once: fp32 global -> fast cvt -> LDS, swizzled content ----
    {
        const int row  = tid >> 2;                      // 0..63
        const int slot = tid & 3;                       // 16B slot
        const int g8   = (slot ^ ((row >> 1) & 3)) * 8; // k-subgroup content
        const float* xsrc = X + (size_t)(m0 + row) * 256 + g8;
        ushort* xdst = Xls + row * 32 + slot * 8;
        #pragma unroll
        for (int t = 0; t < 8; ++t) {
            const float4 a = *(const float4*)(xsrc + t * 32);
            const float4 b = *(const float4*)(xsrc + t * 32 + 4);
            uint4 pk;
            pk.x = fpack2(a.x, a.y); pk.y = fpack2(a.z, a.w);
            pk.z = fpack2(b.x, b.y); pk.w = fpack2(b.z, b.w);
            *(uint4*)(xdst + t * 2048) = pk;
        }
    }
    WSTAGE(Wbuf[0], 0, 0);
    WSTAGE(Wbuf[1], 0, 1);
    __syncthreads();   // one-time full drain: X + first two W stages ready

    const int b2 = m0 >> 8;
    const int n0 = m0 & 255;
    uint* T = (uint*)(S + 8192);       // overlays ring bufs 1+2 (32KB)

    for (int seg = 0; seg < 4; ++seg) {
        f32x4 acc[4][4];
        #pragma unroll
        for (int i = 0; i < 4; ++i)
            #pragma unroll
            for (int j = 0; j < 4; ++j) acc[i][j] = (f32x4){0.f, 0.f, 0.f, 0.f};

        #pragma unroll
        for (int t = 0; t < 8; ++t) {
            if (t < 7) asm volatile("s_waitcnt vmcnt(4)" ::: "memory");
            else       asm volatile("s_waitcnt vmcnt(0)" ::: "memory");
            __builtin_amdgcn_s_barrier();
            if (t < 6) WSTAGE(Wbuf[(t + 2) % 3], seg, t + 2);
            ushort* Wc = Wbuf[t % 3];
            bf16x8 af[4], bfr[4];
            #pragma unroll
            for (int i = 0; i < 4; ++i)
                af[i] = *(const bf16x8*)(Wc + (w * 64 + i * 16 + lj) * 32 + xsl);
            #pragma unroll
            for (int j = 0; j < 4; ++j)
                bfr[j] = *(const bf16x8*)(Xls + t * 2048 + (j * 16 + lj) * 32 + xsl);
            #pragma unroll
            for (int i = 0; i < 4; ++i)
                #pragma unroll
                for (int j = 0; j < 4; ++j)
                    acc[i][j] = __builtin_amdgcn_mfma_f32_16x16x32_bf16(af[i], bfr[j], acc[i][j], 0, 0, 0);
        }

        __builtin_amdgcn_s_barrier();   // all waves done reading ring bufs

        // prefetch next seg's step-0 into buf0 (disjoint from T) — overlaps epilogue
        if (seg < 3) WSTAGE(Wbuf[0], seg + 1, 0);

        // ---- epilogue stage 1: acc -> T[ml 0..63][el 0..255], swizzled ----
        #pragma unroll
        for (int i = 0; i < 4; ++i) {
            const int el0 = w * 64 + i * 16 + lg * 4;
            #pragma unroll
            for (int j = 0; j < 4; ++j) {
                const int ml = j * 16 + lj;
                uint2 pk;
                if (seg == 3) {
                    float z0 = acc[i][j][0] + gbias[el0 + 0];
                    float z1 = acc[i][j][1] + gbias[el0 + 1];
                    float z2 = acc[i][j][2] + gbias[el0 + 2];
                    float z3 = acc[i][j][3] + gbias[el0 + 3];
                    pk.x = fpack2(1.f / (1.f + __expf(-z0)), 1.f / (1.f + __expf(-z1)));
                    pk.y = fpack2(1.f / (1.f + __expf(-z2)), 1.f / (1.f + __expf(-z3)));
                } else {
                    pk.x = fpack2(acc[i][j][0], acc[i][j][1]);
                    pk.y = fpack2(acc[i][j][2], acc[i][j][3]);
                }
                const int wd = (ml * 128 + (el0 >> 1)) ^ ((ml & 7) << 2);
                *(uint2*)(T + wd) = pk;
            }
        }
        asm volatile("s_waitcnt lgkmcnt(0)" ::: "memory");  // T visible (keeps vm prefetch flying)
        __builtin_amdgcn_s_barrier();

        // ---- epilogue stage 2: LDS -> global, coalesced ----
        if (seg < 3) {
            ushort* base = (seg == 0) ? q_ws : (seg == 1) ? k_ws : v_ws;
            #pragma unroll
            for (int hh = 0; hh < 2; ++hh) {
                const int h = w * 2 + hh;
                ushort* gdst = base + ((size_t)(b2 * 8 + h) * 256 + n0) * 32;
                #pragma unroll
                for (int it = 0; it < 4; ++it) {
                    const int ml = it * 16 + (lane >> 2);
                    const int cq = lane & 3;
                    const int wd = (ml * 128 + h * 16 + cq * 4) ^ ((ml & 7) << 2);
                    const uint4 d = *(const uint4*)(T + wd);
                    *(uint4*)(gdst + (size_t)ml * 32 + cq * 8) = d;
                }
            }
        } else {
            const int row  = tid >> 2;
            const int part = tid & 3;
            ushort* gdst = g_ws + (size_t)(m0 + row) * 256;
            #pragma unroll
            for (int r8 = 0; r8 < 8; ++r8) {
                const int wc = r8 * 16 + part * 4;
                const int wd = (row * 128 + wc) ^ ((row & 7) << 2);
                const uint4 d = *(const uint4*)(T + wd);
                *(uint4*)(gdst + wc * 2) = d;
            }
        }

        if (seg < 3) {
            __builtin_amdgcn_s_barrier();       // T reads done (data deps drained lgkm)
            WSTAGE(Wbuf[1], seg + 1, 1);        // buf1 (ex-T) now safe to refill
        }
    }
    #undef WSTAGE
}

// ---------------- Kernel 2: MFMA attention (r10, unchanged) ----------
#define SWZ(c) ((((c) >> 2) & 3) << 5)

__global__ __launch_bounds__(512) void attn_mfma_kernel(
    const ushort* __restrict__ q_ws,
    const ushort* __restrict__ k_ws,
    const ushort* __restrict__ v_ws,
    const ushort* __restrict__ g_ws,
    const float* __restrict__ bias,   // [8][256][256]
    const float* __restrict__ mask,   // [128][256]
    ushort* __restrict__ wa_ws)       // bf16 [32768][256]
{
    __shared__ ushort Ks[256 * 32];
    __shared__ ushort Vt[32 * 256];
    __shared__ ushort Pl[8 * 1024];

    const int tid  = threadIdx.x;
    const int bh   = blockIdx.x >> 1;
    const int half = blockIdx.x & 1;
    const int b2   = bh >> 3;
    const int h    = bh & 7;
    const int w    = tid >> 6;
    const int lane = tid & 63;
    const int lj   = lane & 15;
    const int lg   = lane >> 4;

    // stage K via direct global->LDS (linear)
    {
        const char* gk = (const char*)(k_ws + (size_t)bh * 8192);
        gload_lds16(gk + tid * 16,        (char*)Ks + w * 1024);
        gload_lds16(gk + 8192 + tid * 16, (char*)Ks + 8192 + w * 1024);
    }
    // stage V transposed (register path, swizzled scatter)
    {
        const int cq = tid & 3;
        #pragma unroll
        for (int it = 0; it < 2; ++it) {
            const int n = it * 128 + (tid >> 2);
            uint4 v = *(const uint4*)(v_ws + (size_t)bh * 8192 + n * 32 + cq * 8);
            const ushort* pv = (const ushort*)&v;
            #pragma unroll
            for (int e = 0; e < 8; ++e) {
                const int c = cq * 8 + e;
                const int byte = c * 512 + ((2 * n) ^ SWZ(c));
                Vt[byte >> 1] = pv[e];
            }
        }
    }

    const int q0 = half * 128 + w * 16;
    const bf16x8 qf = *(const bf16x8*)(q_ws + (size_t)bh * 8192 + (size_t)(q0 + lj) * 32 + lg * 8);

    // accumulator init: bias + mask (coalesced), before the barrier
    f32x4 acc[16];
    const float* bbase = bias + (size_t)h * 65536;
    const float* mrow  = mask + (size_t)b2 * 256;
    #pragma unroll
    for (int t = 0; t < 16; ++t) {
        const int col = t * 16 + lj;
        const float mterm = (mrow[col] - 1.0f) * 1e9f;
        #pragma unroll
        for (int r = 0; r < 4; ++r) {
            const int qrow = q0 + lg * 4 + r;
            acc[t][r] = bbase[(size_t)qrow * 256 + col] + mterm;
        }
    }

    __syncthreads();

    #pragma unroll
    for (int t = 0; t < 16; ++t) {
        const bf16x8 kf = *(const bf16x8*)(Ks + (t * 16 + lj) * 32 + lg * 8);
        acc[t] = __builtin_amdgcn_mfma_f32_16x16x32_bf16(qf, kf, acc[t], 0, 0, 0);
    }

    // no-max softmax: exp + per-row sum (rows r; 16 lanes share a row)
    float s[4] = {0.f, 0.f, 0.f, 0.f};
    #pragma unroll
    for (int t = 0; t < 16; ++t)
        #pragma unroll
        for (int r = 0; r < 4; ++r) {
            const float e = __expf(acc[t][r]);
            acc[t][r] = e;
            s[r] += e;
        }
    float inv[4];
    #pragma unroll
    for (int r = 0; r < 4; ++r) {
        float sr = s[r];
        sr += __shfl_xor(sr, 1);
        sr += __shfl_xor(sr, 2);
        sr += __shfl_xor(sr, 4);
        sr += __shfl_xor(sr, 8);
        inv[r] = 1.0f / sr;
    }

    ushort* PlW = Pl + w * 1024;
    f32x4 o0 = {0.f, 0.f, 0.f, 0.f};
    f32x4 o1 = {0.f, 0.f, 0.f, 0.f};
    #pragma unroll
    for (int ch = 0; ch < 4; ++ch) {
        #pragma unroll
        for (int tt = 0; tt < 4; ++tt) {
            const int t = ch * 4 + tt;
            #pragma unroll
            for (int r = 0; r < 4; ++r) {
                const int row  = lg * 4 + r;
                const int byte = row * 128 + ((32 * tt + 2 * lj) ^ (lg << 5));
                PlW[byte >> 1] = f2bf_fast(acc[t][r]);
            }
        }
        #pragma unroll
        for (int kk = 0; kk < 2; ++kk) {
            const int abyte = lj * 128 + ((64 * kk + 16 * lg) ^ SWZ(lj));
            const bf16x8 pa = *(const bf16x8*)(PlW + (abyte >> 1));
            const int ks = ch * 2 + kk;
            {
                const int cr = lj;
                const int vbyte = cr * 512 + ((64 * ks + 16 * lg) ^ SWZ(cr));
                const bf16x8 vb = *(const bf16x8*)(Vt + (vbyte >> 1));
                o0 = __builtin_amdgcn_mfma_f32_16x16x32_bf16(pa, vb, o0, 0, 0, 0);
            }
            {
                const int cr = 16 + lj;
                const int vbyte = cr * 512 + ((64 * ks + 16 * lg) ^ SWZ(cr));
                const bf16x8 vb = *(const bf16x8*)(Vt + (vbyte >> 1));
                o1 = __builtin_amdgcn_mfma_f32_16x16x32_bf16(pa, vb, o1, 0, 0, 0);
            }
        }
    }

    #pragma unroll
    for (int r = 0; r < 4; ++r) {
        const int qrow = q0 + lg * 4 + r;
        const size_t rowbase = ((size_t)(b2 * 256 + qrow)) * 256 + h * 32;
        {
            const float gv = bf2f(g_ws[rowbase + lj]);
            wa_ws[rowbase + lj] = f2bf_fast(o0[r] * inv[r] * gv);
        }
        {
            const float gv = bf2f(g_ws[rowbase + 16 + lj]);
            wa_ws[rowbase + 16 + lj] = f2bf_fast(o1[r] * inv[r] * gv);
        }
    }
}

// ---------------- Kernel 3: MFMA output projection (r10, unchanged) ----------------
__global__ __launch_bounds__(256) void out_mfma_kernel(
    const ushort* __restrict__ WA,   // bf16 [32768][256]
    const ushort* __restrict__ Wob,  // bf16 [256][256]
    const float* __restrict__ bo,    // [256]
    float* __restrict__ out)         // [32768][256]
{
    __shared__ ushort S[20480];
    ushort* const Obuf[2] = { S,        S + 10240 };
    ushort* const Abuf[2] = { S + 8192, S + 18432 };

    const int tid  = threadIdx.x;
    const int w    = tid >> 6;
    const int lane = tid & 63;
    const int lj   = lane & 15;
    const int lg   = lane >> 4;
    const int m0   = blockIdx.x * 64;

    f32x4 acc[4][4];
    #pragma unroll
    for (int i = 0; i < 4; ++i)
        #pragma unroll
        for (int j = 0; j < 4; ++j) acc[i][j] = (f32x4){0.f, 0.f, 0.f, 0.f};

    const int srow = lane >> 2;
    const int scol = (((lane & 3) ^ ((lane >> 3) & 3)) << 3);
    const int xsl  = ((lg ^ ((lj >> 1) & 3)) << 3);

    #define OSTAGE(Odst, Adst, kk) do {                                          \
        _Pragma("unroll")                                                        \
        for (int c = 0; c < 4; ++c) {                                            \
            const int ci = w * 4 + c;                                            \
            gload_lds16(Wob + (size_t)(ci * 16 + srow) * 256 + (kk) + scol,      \
                        (char*)(Odst) + ci * 1024);                              \
        }                                                                        \
        gload_lds16(WA + (size_t)(m0 + w * 16 + srow) * 256 + (kk) + scol,       \
                    (char*)(Adst) + w * 1024);                                   \
    } while (0)

    OSTAGE(Obuf[0], Abuf[0], 0);
    asm volatile("s_waitcnt vmcnt(0)" ::: "memory");
    __builtin_amdgcn_s_barrier();

    #pragma unroll
    for (int t = 0; t < 8; ++t) {
        ushort* Oc = Obuf[t & 1];
        ushort* Ac = Abuf[t & 1];
        if (t < 7) OSTAGE(Obuf[(t + 1) & 1], Abuf[(t + 1) & 1], (t + 1) * 32);
        bf16x8 af[4], bfr[4];
        #pragma unroll
        for (int i = 0; i < 4; ++i)
            af[i] = *(const bf16x8*)(Ac + (i * 16 + lj) * 32 + xsl);
        #pragma unroll
        for (int j = 0; j < 4; ++j)
            bfr[j] = *(const bf16x8*)(Oc + (w * 64 + j * 16 + lj) * 32 + xsl);
        #pragma unroll
        for (int i = 0; i < 4; ++i)
            #pragma unroll
            for (int j = 0; j < 4; ++j)
                acc[i][j] = __builtin_amdgcn_mfma_f32_16x16x32_bf16(af[i], bfr[j], acc[i][j], 0, 0, 0);
        asm volatile("s_waitcnt vmcnt(0)" ::: "memory");
        __builtin_amdgcn_s_barrier();
    }
    #undef OSTAGE

    #pragma unroll
    for (int i = 0; i < 4; ++i) {
        #pragma unroll
        for (int r = 0; r < 4; ++r) {
            const int m = m0 + i * 16 + lg * 4 + r;
            #pragma unroll
            for (int j = 0; j < 4; ++j) {
                const int o = w * 64 + j * 16 + lj;
                out[(size_t)m * 256 + o] = acc[i][j][r] + bo[o];
            }
        }
    }
}

extern "C" void kernel_launch(void* const* d_in, const int* in_sizes, int n_in,
                              void* d_out, int out_size, void* d_ws, size_t ws_size,
                              hipStream_t stream) {
    const float* in_data = (const float*)d_in[0];
    const float* mask    = (const float*)d_in[1];
    const float* nb_bias = (const float*)d_in[2];
    const float* w_qkv   = (const float*)d_in[3];
    const float* w_gate  = (const float*)d_in[4];
    const float* g_bias  = (const float*)d_in[5];
    const float* w_o     = (const float*)d_in[6];
    const float* b_o     = (const float*)d_in[7];
    float* out = (float*)d_out;

    ushort* ws = (ushort*)d_ws;
    const size_t per_head = (size_t)B2 * NHEAD * NSEQ * CDIM;  // 8,388,608
    ushort* q_ws   = ws;
    ushort* k_ws   = q_ws + per_head;
    ushort* v_ws   = k_ws + per_head;
    ushort* g_ws   = v_ws + per_head;                 // [32768][256]
    ushort* wa_ws  = g_ws + (size_t)NROWS * HC;
    ushort* wqkvgb = wa_ws + (size_t)NROWS * HC;      // [1024][256]
    ushort* wob    = wqkvgb + 1024 * 256;             // [256][256]

    convertW_kernel<<<dim3(320), 256, 0, stream>>>(
        w_qkv, w_gate, w_o, wqkvgb, wob);

    qkvg_mfma_kernel<<<dim3(NROWS / 64), 256, 0, stream>>>(
        in_data, wqkvgb, g_bias, q_ws, k_ws, v_ws, g_ws);

    attn_mfma_kernel<<<dim3(B2 * NHEAD * 2), 512, 0, stream>>>(
        q_ws, k_ws, v_ws, g_ws, nb_bias, mask, wa_ws);

    out_mfma_kernel<<<dim3(NROWS / 64), 256, 0, stream>>>(
        wa_ws, wob, b_o, out);
}